// Round 5
// baseline (379.487 us; speedup 1.0000x reference)
//
#include <hip/hip_runtime.h>
#include <cstddef>
#include <cstdint>

#define Bb 16
#define Uu 2048
#define Dd 512
#define BU (Bb*Uu)

typedef short bf16x8 __attribute__((ext_vector_type(8)));
typedef float f32x4 __attribute__((ext_vector_type(4)));

#define ROW_BYTES 208                 // 96 bf16 payload (h32,m32,l32) + 16B pad
#define B_OFF 27040                   // A region: 130*208
#define BSLICE 26624                  // 128 rows * 208B
#define STEP_BYTES (512*ROW_BYTES)    // 106496 per (chunk,tap) full-N B block
#define SMEM_BYTES (B_OFF + 2*BSLICE) // 80288 -> 2 blocks/CU

#define WAITVM(N) asm volatile("s_waitcnt vmcnt(" #N ")" ::: "memory")
#define WAITLGKM0 asm volatile("s_waitcnt lgkmcnt(0)" ::: "memory")

__device__ __forceinline__ unsigned short f2bf(float x){
  unsigned int u = __float_as_uint(x);
  u += 0x7fff + ((u >> 16) & 1);          // RNE
  return (unsigned short)(u >> 16);
}
__device__ __forceinline__ float bf2f(unsigned short b){
  return __uint_as_float(((unsigned int)b) << 16);
}

union U16x8 { unsigned short s[8]; uint4 v; };

__device__ __forceinline__ void split3(float x, unsigned short& h, unsigned short& m, unsigned short& l){
  h = f2bf(x);
  float r1 = x - bf2f(h);
  m = f2bf(r1);
  float r2 = r1 - bf2f(m);
  l = f2bf(r2);
}

// ---------------- pack conv_w -> Bpack[step=(chunk*3+tap)][n(512)][208B: bh32|bm32|bl32|pad]
__global__ __launch_bounds__(256) void pack_b_kernel(const float* __restrict__ conv_w,
                                                     char* __restrict__ Bpack){
  int idx = blockIdx.x * 256 + threadIdx.x;    // < 48*2048
  int step = idx >> 11;
  int rem = idx & 2047;
  int n = rem >> 2, u = rem & 3;
  int chunk = step / 3, tap = step - chunk * 3;
  int c0 = chunk * 32 + u * 8;
  U16x8 H, M, L;
  #pragma unroll
  for (int j = 0; j < 8; ++j){
    float w = conv_w[((size_t)n * Dd + (c0 + j)) * 3 + tap];
    split3(w, H.s[j], M.s[j], L.s[j]);
  }
  char* dst = Bpack + (size_t)step * STEP_BYTES + n * ROW_BYTES + u * 16;
  *(uint4*)(dst)       = H.v;
  *(uint4*)(dst + 64)  = M.v;
  *(uint4*)(dst + 128) = L.v;
}

// ---------------- helpers
__device__ __forceinline__ void stage_A_direct(char* smem, const float* __restrict__ xsb,
                                               int u0, int c0, int tid){
  #pragma unroll
  for (int it = 0; it < 2; ++it){
    if (it == 0 || tid < 8){
      int t = tid + it * 512;                 // 520 tasks: 130 rows x 4 col-groups
      int r = t >> 2, cg = t & 3;
      int uu = u0 - 1 + r;
      float x[8];
      if (uu >= 0 && uu < Uu){
        const float* p = xsb + (size_t)uu * Dd + c0 + cg * 8;
        float4 a = *(const float4*)p;
        float4 b = *(const float4*)(p + 4);
        x[0]=a.x; x[1]=a.y; x[2]=a.z; x[3]=a.w; x[4]=b.x; x[5]=b.y; x[6]=b.z; x[7]=b.w;
      } else {
        #pragma unroll
        for (int j = 0; j < 8; ++j) x[j] = 0.f;
      }
      U16x8 H, M, L;
      #pragma unroll
      for (int j = 0; j < 8; ++j) split3(x[j], H.s[j], M.s[j], L.s[j]);
      char* dst = smem + r * ROW_BYTES + cg * 16;
      *(uint4*)(dst)       = H.v;
      *(uint4*)(dst + 64)  = M.v;
      *(uint4*)(dst + 128) = L.v;
    }
  }
}

__device__ __forceinline__ void gll16(const char* g, char* l){
  __builtin_amdgcn_global_load_lds(
      (const __attribute__((address_space(1))) unsigned int*)g,
      (__attribute__((address_space(3))) unsigned int*)l, 16, 0, 0);
}

// 26 groups of 1024B; wave wv handles g = wv, wv+8, wv+16, (+24 if wv<2).
// Per-wave vm issue count: wv<2 -> 4, else 3 (uniform per wave; counted waits rely on this).
__device__ __forceinline__ void stage_slice(char* ldsB, const char* __restrict__ src,
                                            int lane, int wv){
  const char* g = src + wv * 1024 + lane * 16;
  char* l = ldsB + wv * 1024;
  gll16(g, l);
  gll16(g + 8192,  l + 8192);
  gll16(g + 16384, l + 16384);
  if (wv < 2) gll16(g + 24576, l + 24576);
}

__device__ __forceinline__ bf16x8 ldfrag(const char* p){
  return __builtin_bit_cast(bf16x8, *(const uint4*)p);
}

// ---------------- conv GEMM: 128x128 tile, 2 blocks/CU, counted-vmcnt 2-phase pipeline
__global__ __launch_bounds__(512, 4) void conv_mfma_full_kernel(
    const float* __restrict__ xs, const char* __restrict__ Bpack,
    const float* __restrict__ conv_b, const float* __restrict__ lin_w,
    float* __restrict__ partial)
{
  __shared__ __align__(16) char smem[SMEM_BYTES];
  const int tid = threadIdx.x;
  const int lane = tid & 63, wv = tid >> 6;
  const int wm = wv & 3;
  const int wn = wv >> 2;
  const int cs = blockIdx.x >> 8;
  const int bt = blockIdx.x & 255;
  const int b = bt >> 4, ut = bt & 15;
  const int u0 = ut * 128;
  const float* xsb = xs + (size_t)b * Uu * Dd;
  const int li = lane & 15, lg = lane >> 4;

  f32x4 acc[2][4];
  #pragma unroll
  for (int m = 0; m < 2; ++m)
    #pragma unroll
    for (int n = 0; n < 4; ++n){
      f32x4 z = {0.f, 0.f, 0.f, 0.f};
      acc[m][n] = z;
    }

  // prologue: A chunk0 (plain LDS stores), B step0 -> buf0; one full drain
  stage_A_direct(smem, xsb, u0, 0, tid);
  stage_slice(smem + B_OFF, Bpack + cs * BSLICE, lane, wv);
  __syncthreads();   // vmcnt(0)+lgkm drain once: stage(0) landed, A visible

  for (int chunk = 0; chunk < 16; ++chunk){
    const bool more = (chunk < 15);
    #pragma unroll
    for (int tap = 0; tap < 3; ++tap){
      const int p = chunk * 3 + tap;
      const int buf = p & 1;
      const bool apf_now = (tap == 2) && more;

      // 1. A-prefetch for next chunk (4 vm loads per wave, uniform):
      //    every lane: tasks tid (2 loads); lane0 of each wave: task 512+wv (2 loads)
      float4 apf0, apf1, apf2, apf3;
      int ar_ = 0, acg_ = 0, r2_ = 0, cg2_ = 0;
      if (apf_now){
        int c0n = (chunk + 1) * 32;
        ar_ = tid >> 2; acg_ = tid & 3;
        int uu = u0 - 1 + ar_;
        if (uu >= 0 && uu < Uu){
          const float* pp = xsb + (size_t)uu * Dd + c0n + acg_ * 8;
          apf0 = *(const float4*)pp;
          apf1 = *(const float4*)(pp + 4);
        } else {
          apf0 = make_float4(0.f,0.f,0.f,0.f); apf1 = apf0;
        }
        int t2 = 512 + wv;
        r2_ = t2 >> 2; cg2_ = t2 & 3;
        apf2 = make_float4(0.f,0.f,0.f,0.f); apf3 = apf2;
        if (lane == 0){
          int uu2 = u0 - 1 + r2_;
          if (uu2 >= 0 && uu2 < Uu){
            const float* p2 = xsb + (size_t)uu2 * Dd + c0n + cg2_ * 8;
            apf2 = *(const float4*)p2;
            apf3 = *(const float4*)(p2 + 4);
          }
        }
      }

      // 2. stage next step's B slice into the other buffer (3/4 loads per wave)
      if (p < 47)
        stage_slice(smem + B_OFF + (buf ^ 1) * BSLICE,
                    Bpack + (size_t)(p + 1) * STEP_BYTES + cs * BSLICE, lane, wv);

      // 3. counted wait: retire stage(p) (and, at p=47, everything)
      if (p == 47)            { WAITVM(0); }
      else if (apf_now)       { if (wv < 2) WAITVM(8); else WAITVM(7); }
      else                    { if (wv < 2) WAITVM(4); else WAITVM(3); }
      __builtin_amdgcn_sched_barrier(0);

      // 4. A fragments (tap-shifted rows)
      bf16x8 a[2][3];
      #pragma unroll
      for (int m = 0; m < 2; ++m){
        const char* ar = smem + (size_t)(wm * 32 + m * 16 + li + tap) * ROW_BYTES + lg * 16;
        a[m][0] = ldfrag(ar);
        a[m][1] = ldfrag(ar + 64);
        a[m][2] = ldfrag(ar + 128);
      }

      // 5. B fragments + MFMA (6-pass split product)
      __builtin_amdgcn_s_setprio(1);
      const char* bbase = smem + B_OFF + buf * BSLICE;
      #pragma unroll
      for (int n = 0; n < 4; ++n){
        const char* br = bbase + (size_t)(wn * 64 + n * 16 + li) * ROW_BYTES + lg * 16;
        bf16x8 bh = ldfrag(br);
        bf16x8 bm = ldfrag(br + 64);
        bf16x8 bl = ldfrag(br + 128);
        #pragma unroll
        for (int m = 0; m < 2; ++m){
          acc[m][n] = __builtin_amdgcn_mfma_f32_16x16x32_bf16(a[m][0], bh, acc[m][n], 0, 0, 0); // hh
          acc[m][n] = __builtin_amdgcn_mfma_f32_16x16x32_bf16(a[m][1], bh, acc[m][n], 0, 0, 0); // mh
          acc[m][n] = __builtin_amdgcn_mfma_f32_16x16x32_bf16(a[m][0], bm, acc[m][n], 0, 0, 0); // hm
          acc[m][n] = __builtin_amdgcn_mfma_f32_16x16x32_bf16(a[m][0], bl, acc[m][n], 0, 0, 0); // hl
          acc[m][n] = __builtin_amdgcn_mfma_f32_16x16x32_bf16(a[m][2], bh, acc[m][n], 0, 0, 0); // lh
          acc[m][n] = __builtin_amdgcn_mfma_f32_16x16x32_bf16(a[m][1], bm, acc[m][n], 0, 0, 0); // mm
        }
      }
      __builtin_amdgcn_s_setprio(0);

      // 6. tap2: A-rewrite slot (barrier-separated; no vm drain)
      if (apf_now){
        __builtin_amdgcn_s_barrier();          // all waves' A-reads of this chunk consumed
        U16x8 H, M, L;
        float x[8];
        x[0]=apf0.x; x[1]=apf0.y; x[2]=apf0.z; x[3]=apf0.w;
        x[4]=apf1.x; x[5]=apf1.y; x[6]=apf1.z; x[7]=apf1.w;
        #pragma unroll
        for (int jj = 0; jj < 8; ++jj) split3(x[jj], H.s[jj], M.s[jj], L.s[jj]);
        char* dst = smem + ar_ * ROW_BYTES + acg_ * 16;
        *(uint4*)(dst)       = H.v;
        *(uint4*)(dst + 64)  = M.v;
        *(uint4*)(dst + 128) = L.v;
        if (lane == 0){
          float y[8];
          y[0]=apf2.x; y[1]=apf2.y; y[2]=apf2.z; y[3]=apf2.w;
          y[4]=apf3.x; y[5]=apf3.y; y[6]=apf3.z; y[7]=apf3.w;
          #pragma unroll
          for (int jj = 0; jj < 8; ++jj) split3(y[jj], H.s[jj], M.s[jj], L.s[jj]);
          char* dst2 = smem + r2_ * ROW_BYTES + cg2_ * 16;
          *(uint4*)(dst2)       = H.v;
          *(uint4*)(dst2 + 64)  = M.v;
          *(uint4*)(dst2 + 128) = L.v;
        }
        WAITLGKM0;                             // A-writes ordered before phase-end barrier
        __builtin_amdgcn_sched_barrier(0);
      }
      __builtin_amdgcn_s_barrier();            // phase end (raw: stage(p+1) stays in flight)
    }
  }

  // ---- epilogue: partial dot over this block's 128 cols
  __syncthreads();
  float* pbuf = (float*)smem;                  // [128 frames][2]
  #pragma unroll
  for (int m = 0; m < 2; ++m){
    float s0 = 0.f, s1 = 0.f, s2 = 0.f, s3 = 0.f;
    #pragma unroll
    for (int n = 0; n < 4; ++n){
      int col = cs * 128 + wn * 64 + n * 16 + li;
      float cb = conv_b[col], lw = lin_w[col];
      f32x4 v = acc[m][n];
      float h;
      h = v[0] + cb; h = h > 0.f ? h : 0.f; s0 += h * lw;
      h = v[1] + cb; h = h > 0.f ? h : 0.f; s1 += h * lw;
      h = v[2] + cb; h = h > 0.f ? h : 0.f; s2 += h * lw;
      h = v[3] + cb; h = h > 0.f ? h : 0.f; s3 += h * lw;
    }
    #pragma unroll
    for (int msk = 1; msk < 16; msk <<= 1){
      s0 += __shfl_xor(s0, msk); s1 += __shfl_xor(s1, msk);
      s2 += __shfl_xor(s2, msk); s3 += __shfl_xor(s3, msk);
    }
    if (li == 0){
      int fr = wm * 32 + m * 16 + lg * 4;
      pbuf[(fr + 0) * 2 + wn] = s0;
      pbuf[(fr + 1) * 2 + wn] = s1;
      pbuf[(fr + 2) * 2 + wn] = s2;
      pbuf[(fr + 3) * 2 + wn] = s3;
    }
  }
  __syncthreads();
  if (tid < 128){
    float pv = pbuf[tid * 2] + pbuf[tid * 2 + 1];
    partial[(size_t)cs * BU + (size_t)b * Uu + u0 + tid] = pv;
  }
}

// ---------------- fused alpha + sequential faithful scan (one wave per batch)
__global__ __launch_bounds__(64) void scan_kernel(
    const float* __restrict__ partial, const float* __restrict__ lin_b,
    const int* __restrict__ xlens, const int* __restrict__ ylens,
    float* __restrict__ wA, float* __restrict__ wB,
    int* __restrict__ fire_pos, int* __restrict__ nf,
    float* __restrict__ out_sum)
{
  __shared__ float salpha[Uu];
  int b = blockIdx.x;
  int lane = threadIdx.x;
  int xl = xlens[b];
  float lb = lin_b[0];

  // pass 1: alpha from partials -> LDS + total sum
  float sum = 0.f;
  for (int u0 = 0; u0 < Uu; u0 += 64){
    int u = u0 + lane;
    size_t ix = (size_t)b * Uu + u;
    float v = lb + partial[ix] + partial[BU + ix] + partial[2 * BU + ix] + partial[3 * BU + ix];
    float a = 1.f / (1.f + expf(-v));
    if (u >= xl) a = 0.f;
    salpha[u] = a;
    sum += a;
  }
  #pragma unroll
  for (int m = 1; m < 64; m <<= 1) sum += __shfl_xor(sum, m);
  float sa = sum;
  float beta = sa / (float)ylens[b] - 1e-4f;
  if (lane == 0) out_sum[b] = sa;

  // pass 2: faithful sequential scan
  float prev = 0.f;
  int cnt = 0;
  for (int u0 = 0; u0 < Uu; u0 += 64) {
    if (u0 >= xl) break;
    float val = salpha[u0 + lane];
    float mywa = 0.f, mywb = 0.f;
    float a_cur = __shfl(val, 0);
    #pragma unroll 4
    for (int i = 0; i < 64; ++i) {
      float a_next = __shfl(val, (i + 1) & 63);
      float nw = prev + a_cur;
      float left = beta - prev;
      float right = nw - beta;
      bool fired = nw >= beta;
      if (lane == i) { mywa = left; mywb = right; }
      if (fired) {
        if (lane == 0) fire_pos[(b << 11) + cnt] = u0 + i;
        ++cnt;
      }
      prev = fired ? right : nw;
      a_cur = a_next;
    }
    wA[(size_t)b * Uu + u0 + lane] = mywa;
    wB[(size_t)b * Uu + u0 + lane] = mywb;
  }
  if (lane == 0) nf[b] = cnt;
}

// ---------------- segmented gather -> h_cif — unchanged (passed)
__global__ __launch_bounds__(512) void gather_kernel(
    const float* __restrict__ xs, const float* __restrict__ wA, const float* __restrict__ wB,
    const int* __restrict__ fire_pos, const int* __restrict__ nf,
    float* __restrict__ out, int umax)
{
  int t = blockIdx.x, b = blockIdx.y;
  int tid = threadIdx.x;
  float* o = out + ((size_t)b * umax + t) * Dd;
  int n = nf[b];
  if (t >= n) { o[tid] = 0.f; return; }
  int start = (t == 0) ? 0 : fire_pos[(b << 11) + t - 1];
  int end = fire_pos[(b << 11) + t];
  const float* xb = xs + (size_t)b * Uu * Dd;
  float acc = 0.f;
  for (int u = start; u <= end; ++u) {
    float w = (t > 0 && u == start) ? wB[(size_t)b * Uu + u] : wA[(size_t)b * Uu + u];
    acc += w * xb[(size_t)u * Dd + tid];
  }
  o[tid] = acc;
}

extern "C" void kernel_launch(void* const* d_in, const int* in_sizes, int n_in,
                              void* d_out, int out_size, void* d_ws, size_t ws_size,
                              hipStream_t stream) {
  const float* xs     = (const float*)d_in[0];
  const int*   xlens  = (const int*)d_in[1];
  const int*   ylens  = (const int*)d_in[2];
  const float* conv_w = (const float*)d_in[3];
  const float* conv_b = (const float*)d_in[4];
  const float* lin_w  = (const float*)d_in[5];
  const float* lin_b  = (const float*)d_in[6];
  float* out = (float*)d_out;
  int umax = (out_size - Bb) / (Bb * Dd);

  char* ws = (char*)d_ws;
  char*  Bpack    = ws;                                      // 48*106496 = 5,111,808
  float* partial  = (float*)(ws + 48 * (size_t)STEP_BYTES);  // 4*BU*4 = 512KB
  float* wAv      = partial + 4 * BU;
  float* wBv      = wAv + BU;
  int*   fire_pos = (int*)(wBv + BU);
  int*   nf       = (int*)(fire_pos + BU);

  pack_b_kernel<<<(48 * 2048) / 256, 256, 0, stream>>>(conv_w, Bpack);
  conv_mfma_full_kernel<<<1024, 512, 0, stream>>>(xs, Bpack, conv_b, lin_w, partial);
  scan_kernel<<<Bb, 64, 0, stream>>>(partial, lin_b, xlens, ylens, wAv, wBv, fire_pos, nf,
                                     out + (size_t)Bb * umax * Dd);
  if (umax > 0)
    gather_kernel<<<dim3(umax, Bb), 512, 0, stream>>>(xs, wAv, wBv, fire_pos, nf, out, umax);
}

// Round 6
// 272.367 us; speedup vs baseline: 1.3933x; 1.3933x over previous
//
#include <hip/hip_runtime.h>
#include <cstddef>
#include <cstdint>

#define Bb 16
#define Uu 2048
#define Dd 512
#define BU (Bb*Uu)

typedef short bf16x8 __attribute__((ext_vector_type(8)));
typedef float f32x4 __attribute__((ext_vector_type(4)));

#define ROW_BYTES 144                 // 64B h + 64B m + 16B pad
#define A_BYTES 18720                 // 130 rows * 144
#define B_SLICE 18432                 // 128 rows * 144
#define B_BASE (2*A_BYTES)            // 37440
#define STEP_BYTES (512*ROW_BYTES)    // 73728 per (chunk,tap) full-N B block
#define SMEM_BYTES (B_BASE + 2*B_SLICE) // 74304 -> 2 blocks/CU

#define WAITVM(N) asm volatile("s_waitcnt vmcnt(" #N ")" ::: "memory")
#define WAITLGKM0 asm volatile("s_waitcnt lgkmcnt(0)" ::: "memory")

__device__ __forceinline__ unsigned short f2bf(float x){
  unsigned int u = __float_as_uint(x);
  u += 0x7fff + ((u >> 16) & 1);          // RNE
  return (unsigned short)(u >> 16);
}
__device__ __forceinline__ float bf2f(unsigned short b){
  return __uint_as_float(((unsigned int)b) << 16);
}

union U16x8 { unsigned short s[8]; uint4 v; };

__device__ __forceinline__ void split2(float x, unsigned short& h, unsigned short& m){
  h = f2bf(x);
  float r1 = x - bf2f(h);
  m = f2bf(r1);
}

// ---------------- pack conv_w -> Bpack[step=(chunk*3+tap)][n(512)][144B: bh32|bm32|pad]
// coalesced: each thread reads 24 contiguous floats (8 channels x 3 taps) for one n
__global__ __launch_bounds__(256) void pack_b_kernel(const float* __restrict__ conv_w,
                                                     char* __restrict__ Bpack){
  int idx = blockIdx.x * 256 + threadIdx.x;    // < 512*64
  int n = idx >> 6, cg = idx & 63;
  int chunk = cg >> 2, sub = cg & 3, c0 = cg << 3;
  const float* src = conv_w + (size_t)n * (Dd * 3) + (size_t)c0 * 3;
  float w[24];
  #pragma unroll
  for (int j = 0; j < 24; ++j) w[j] = src[j];
  #pragma unroll
  for (int tap = 0; tap < 3; ++tap){
    U16x8 H, M;
    #pragma unroll
    for (int j = 0; j < 8; ++j) split2(w[j * 3 + tap], H.s[j], M.s[j]);
    char* dst = Bpack + (size_t)(chunk * 3 + tap) * STEP_BYTES + n * ROW_BYTES + sub * 16;
    *(uint4*)dst = H.v;
    *(uint4*)(dst + 64) = M.v;
  }
}

// ---------------- helpers
__device__ __forceinline__ void stage_A_direct(char* abuf, const float* __restrict__ xsb,
                                               int u0, int c0, int tid){
  #pragma unroll
  for (int it = 0; it < 2; ++it){
    if (it == 0 || tid < 8){
      int t = tid + it * 512;                 // 520 tasks: 130 rows x 4 col-groups
      int r = t >> 2, cg = t & 3;
      int uu = u0 - 1 + r;
      float x[8];
      if (uu >= 0 && uu < Uu){
        const float* p = xsb + (size_t)uu * Dd + c0 + cg * 8;
        float4 a = *(const float4*)p;
        float4 b = *(const float4*)(p + 4);
        x[0]=a.x; x[1]=a.y; x[2]=a.z; x[3]=a.w; x[4]=b.x; x[5]=b.y; x[6]=b.z; x[7]=b.w;
      } else {
        #pragma unroll
        for (int j = 0; j < 8; ++j) x[j] = 0.f;
      }
      U16x8 H, M;
      #pragma unroll
      for (int j = 0; j < 8; ++j) split2(x[j], H.s[j], M.s[j]);
      char* dst = abuf + r * ROW_BYTES + cg * 16;
      *(uint4*)(dst)      = H.v;
      *(uint4*)(dst + 64) = M.v;
    }
  }
}

__device__ __forceinline__ void gll16(const char* g, char* l){
  __builtin_amdgcn_global_load_lds(
      (const __attribute__((address_space(1))) unsigned int*)g,
      (__attribute__((address_space(3))) unsigned int*)l, 16, 0, 0);
}

// 18432B slice = 18 groups of 1024B; wave wv: groups wv, wv+8, (+16 if wv<2)
// vm issues per wave: wv<2 -> 3, else 2 (uniform; counted waits rely on this)
__device__ __forceinline__ void stage_slice(char* ldsB, const char* __restrict__ src,
                                            int lane, int wv){
  const char* g = src + wv * 1024 + lane * 16;
  char* l = ldsB + wv * 1024;
  gll16(g, l);
  gll16(g + 8192, l + 8192);
  if (wv < 2) gll16(g + 16384, l + 16384);
}

__device__ __forceinline__ bf16x8 ldfrag(const char* p){
  return __builtin_bit_cast(bf16x8, *(const uint4*)p);
}

// ---------------- conv GEMM: 128x128 tile, 2 blocks/CU, A+B double-buffered,
// 4-pass bf16x2 split product, counted-vmcnt pipeline
__global__ __launch_bounds__(512, 4) void conv_mfma_full_kernel(
    const float* __restrict__ xs, const char* __restrict__ Bpack,
    const float* __restrict__ conv_b, const float* __restrict__ lin_w,
    float* __restrict__ partial)
{
  __shared__ __align__(16) char smem[SMEM_BYTES];
  const int tid = threadIdx.x;
  const int lane = tid & 63, wv = tid >> 6;
  const int wm = wv & 3;                      // 4 M-groups of 32 rows
  const int wn = wv >> 2;                     // 2 N-groups of 64 cols
  const int cs = blockIdx.x >> 8;             // col slice 0..3
  const int bt = blockIdx.x & 255;
  const int b = bt >> 4, ut = bt & 15;
  const int u0 = ut * 128;
  const float* xsb = xs + (size_t)b * Uu * Dd;
  const int li = lane & 15, lg = lane >> 4;

  f32x4 acc[2][4];
  #pragma unroll
  for (int m = 0; m < 2; ++m)
    #pragma unroll
    for (int n = 0; n < 4; ++n){
      f32x4 z = {0.f, 0.f, 0.f, 0.f};
      acc[m][n] = z;
    }

  // prologue: A chunk0 -> Abuf0 (plain stores), B step0 -> Bbuf0; full drain once
  stage_A_direct(smem, xsb, u0, 0, tid);
  stage_slice(smem + B_BASE, Bpack + cs * B_SLICE, lane, wv);
  __syncthreads();

  for (int chunk = 0; chunk < 16; ++chunk){
    const bool more = (chunk < 15);
    const char* aC = smem + (chunk & 1) * A_BYTES;
    char* aN = smem + ((chunk & 1) ^ 1) * A_BYTES;
    #pragma unroll
    for (int tap = 0; tap < 3; ++tap){
      const int p = chunk * 3 + tap;
      const int bbuf = p & 1;
      const bool apf_now = (tap == 2) && more;

      // 1. A-prefetch for next chunk (4 vm loads per wave, uniform)
      float4 apf0, apf1, apf2, apf3;
      int ar_ = 0, acg_ = 0, r2_ = 0, cg2_ = 0;
      if (apf_now){
        int c0n = (chunk + 1) * 32;
        ar_ = tid >> 2; acg_ = tid & 3;
        int uu = u0 - 1 + ar_;
        if (uu >= 0 && uu < Uu){
          const float* pp = xsb + (size_t)uu * Dd + c0n + acg_ * 8;
          apf0 = *(const float4*)pp;
          apf1 = *(const float4*)(pp + 4);
        } else {
          apf0 = make_float4(0.f,0.f,0.f,0.f); apf1 = apf0;
        }
        int t2 = 512 + wv;
        r2_ = t2 >> 2; cg2_ = t2 & 3;
        apf2 = make_float4(0.f,0.f,0.f,0.f); apf3 = apf2;
        if (lane == 0){
          int uu2 = u0 - 1 + r2_;
          if (uu2 >= 0 && uu2 < Uu){
            const float* p2 = xsb + (size_t)uu2 * Dd + c0n + cg2_ * 8;
            apf2 = *(const float4*)p2;
            apf3 = *(const float4*)(p2 + 4);
          }
        }
        __builtin_amdgcn_sched_barrier(0);    // pin apf issue before stage
      }

      // 2. stage next step's B slice into the other buffer (3/2 loads per wave)
      if (p < 47)
        stage_slice(smem + B_BASE + (bbuf ^ 1) * B_SLICE,
                    Bpack + (size_t)(p + 1) * STEP_BYTES + cs * B_SLICE, lane, wv);

      // 3. counted wait: retire stage(p); leave stage(p+1) [+apf until after MFMA]
      if (p == 47)            { WAITVM(0); }
      else if (apf_now)       { if (wv < 2) WAITVM(7); else WAITVM(6); }
      else                    { if (wv < 2) WAITVM(3); else WAITVM(2); }
      __builtin_amdgcn_sched_barrier(0);

      // 4. A fragments (tap-shifted rows), 2 splits
      bf16x8 a[2][2];
      #pragma unroll
      for (int m = 0; m < 2; ++m){
        const char* ar = aC + (size_t)(wm * 32 + m * 16 + li + tap) * ROW_BYTES + lg * 16;
        a[m][0] = ldfrag(ar);
        a[m][1] = ldfrag(ar + 64);
      }

      // 5. B fragments + MFMA (4-pass split product: (ah+am)*(bh+bm))
      __builtin_amdgcn_s_setprio(1);
      const char* bbase = smem + B_BASE + bbuf * B_SLICE;
      #pragma unroll
      for (int n = 0; n < 4; ++n){
        const char* br = bbase + (size_t)(wn * 64 + n * 16 + li) * ROW_BYTES + lg * 16;
        bf16x8 bh = ldfrag(br);
        bf16x8 bm = ldfrag(br + 64);
        #pragma unroll
        for (int m = 0; m < 2; ++m){
          acc[m][n] = __builtin_amdgcn_mfma_f32_16x16x32_bf16(a[m][0], bh, acc[m][n], 0, 0, 0); // hh
          acc[m][n] = __builtin_amdgcn_mfma_f32_16x16x32_bf16(a[m][1], bh, acc[m][n], 0, 0, 0); // mh
          acc[m][n] = __builtin_amdgcn_mfma_f32_16x16x32_bf16(a[m][0], bm, acc[m][n], 0, 0, 0); // hm
          acc[m][n] = __builtin_amdgcn_mfma_f32_16x16x32_bf16(a[m][1], bm, acc[m][n], 0, 0, 0); // mm
        }
      }
      __builtin_amdgcn_s_setprio(0);

      // 6. tap2: convert+write next chunk's A into the OTHER A buffer (no extra barrier)
      if (apf_now){
        if (wv < 2) { WAITVM(3); } else { WAITVM(2); }   // retire apf, keep stage(p+1)
        __builtin_amdgcn_sched_barrier(0);
        U16x8 H, M;
        float x[8];
        x[0]=apf0.x; x[1]=apf0.y; x[2]=apf0.z; x[3]=apf0.w;
        x[4]=apf1.x; x[5]=apf1.y; x[6]=apf1.z; x[7]=apf1.w;
        #pragma unroll
        for (int jj = 0; jj < 8; ++jj) split2(x[jj], H.s[jj], M.s[jj]);
        char* dst = aN + ar_ * ROW_BYTES + acg_ * 16;
        *(uint4*)(dst)      = H.v;
        *(uint4*)(dst + 64) = M.v;
        if (lane == 0){
          float y[8];
          y[0]=apf2.x; y[1]=apf2.y; y[2]=apf2.z; y[3]=apf2.w;
          y[4]=apf3.x; y[5]=apf3.y; y[6]=apf3.z; y[7]=apf3.w;
          #pragma unroll
          for (int jj = 0; jj < 8; ++jj) split2(y[jj], H.s[jj], M.s[jj]);
          char* dst2 = aN + r2_ * ROW_BYTES + cg2_ * 16;
          *(uint4*)(dst2)      = H.v;
          *(uint4*)(dst2 + 64) = M.v;
        }
        WAITLGKM0;                            // A-writes visible before phase-end barrier
        __builtin_amdgcn_sched_barrier(0);
      }
      __builtin_amdgcn_s_barrier();           // phase end (stage(p+1) stays in flight)
    }
  }

  // ---- epilogue: relu(h+conv_b)*lin_w partial dot over this block's 128 cols
  __syncthreads();
  float* pbuf = (float*)smem;                 // [128 frames][2]
  #pragma unroll
  for (int m = 0; m < 2; ++m){
    float s0 = 0.f, s1 = 0.f, s2 = 0.f, s3 = 0.f;
    #pragma unroll
    for (int n = 0; n < 4; ++n){
      int col = cs * 128 + wn * 64 + n * 16 + li;
      float cb = conv_b[col], lw = lin_w[col];
      f32x4 v = acc[m][n];
      float h;
      h = v[0] + cb; h = h > 0.f ? h : 0.f; s0 += h * lw;
      h = v[1] + cb; h = h > 0.f ? h : 0.f; s1 += h * lw;
      h = v[2] + cb; h = h > 0.f ? h : 0.f; s2 += h * lw;
      h = v[3] + cb; h = h > 0.f ? h : 0.f; s3 += h * lw;
    }
    #pragma unroll
    for (int msk = 1; msk < 16; msk <<= 1){
      s0 += __shfl_xor(s0, msk); s1 += __shfl_xor(s1, msk);
      s2 += __shfl_xor(s2, msk); s3 += __shfl_xor(s3, msk);
    }
    if (li == 0){
      int fr = wm * 32 + m * 16 + lg * 4;
      pbuf[(fr + 0) * 2 + wn] = s0;
      pbuf[(fr + 1) * 2 + wn] = s1;
      pbuf[(fr + 2) * 2 + wn] = s2;
      pbuf[(fr + 3) * 2 + wn] = s3;
    }
  }
  __syncthreads();
  if (tid < 128){
    float pv = pbuf[tid * 2] + pbuf[tid * 2 + 1];
    partial[(size_t)cs * BU + (size_t)b * Uu + u0 + tid] = pv;
  }
}

// ---------------- fused alpha + scalar-chain scan (one wave per batch)
__global__ __launch_bounds__(64) void scan_kernel(
    const float* __restrict__ partial, const float* __restrict__ lin_b,
    const int* __restrict__ xlens, const int* __restrict__ ylens,
    float* __restrict__ wA, float* __restrict__ wB,
    int* __restrict__ fire_pos, int* __restrict__ nf,
    float* __restrict__ out_sum)
{
  __shared__ float salpha[Uu];
  int b = blockIdx.x;
  int lane = threadIdx.x;
  int xl = xlens[b];
  float lb = lin_b[0];

  // pass 1: alpha from partials -> LDS + total sum
  float sum = 0.f;
  for (int u0 = 0; u0 < Uu; u0 += 64){
    int u = u0 + lane;
    size_t ix = (size_t)b * Uu + u;
    float v = lb + partial[ix] + partial[BU + ix] + partial[2 * BU + ix] + partial[3 * BU + ix];
    float a = 1.f / (1.f + expf(-v));
    if (u >= xl) a = 0.f;
    salpha[u] = a;
    sum += a;
  }
  #pragma unroll
  for (int m = 1; m < 64; m <<= 1) sum += __shfl_xor(sum, m);
  float sa = sum;
  float beta = sa / (float)ylens[b] - 1e-4f;
  if (lane == 0) out_sum[b] = sa;

  // pass 2: faithful sequential scan; broadcast via readlane (short VALU chain)
  float prev = 0.f;
  int cnt = 0;
  for (int u0 = 0; u0 < Uu; u0 += 64) {
    if (u0 >= xl) break;
    float val = salpha[u0 + lane];            // single wave: no barrier needed
    float mywa = 0.f, mywb = 0.f;
    #pragma unroll
    for (int i = 0; i < 64; ++i) {
      float a_cur = __builtin_bit_cast(float,
          __builtin_amdgcn_readlane(__builtin_bit_cast(int, val), i));
      float nw = prev + a_cur;                // exact reference rounding order
      float left = beta - prev;
      float right = nw - beta;
      bool fired = nw >= beta;
      if (lane == i) { mywa = left; mywb = right; }
      if (fired) {
        if (lane == 0) fire_pos[(b << 11) + cnt] = u0 + i;
        ++cnt;
      }
      prev = fired ? right : nw;
    }
    wA[(size_t)b * Uu + u0 + lane] = mywa;
    wB[(size_t)b * Uu + u0 + lane] = mywb;
  }
  if (lane == 0) nf[b] = cnt;
}

// ---------------- segmented gather -> h_cif — unchanged (passed)
__global__ __launch_bounds__(512) void gather_kernel(
    const float* __restrict__ xs, const float* __restrict__ wA, const float* __restrict__ wB,
    const int* __restrict__ fire_pos, const int* __restrict__ nf,
    float* __restrict__ out, int umax)
{
  int t = blockIdx.x, b = blockIdx.y;
  int tid = threadIdx.x;
  float* o = out + ((size_t)b * umax + t) * Dd;
  int n = nf[b];
  if (t >= n) { o[tid] = 0.f; return; }
  int start = (t == 0) ? 0 : fire_pos[(b << 11) + t - 1];
  int end = fire_pos[(b << 11) + t];
  const float* xb = xs + (size_t)b * Uu * Dd;
  float acc = 0.f;
  for (int u = start; u <= end; ++u) {
    float w = (t > 0 && u == start) ? wB[(size_t)b * Uu + u] : wA[(size_t)b * Uu + u];
    acc += w * xb[(size_t)u * Dd + tid];
  }
  o[tid] = acc;
}

extern "C" void kernel_launch(void* const* d_in, const int* in_sizes, int n_in,
                              void* d_out, int out_size, void* d_ws, size_t ws_size,
                              hipStream_t stream) {
  const float* xs     = (const float*)d_in[0];
  const int*   xlens  = (const int*)d_in[1];
  const int*   ylens  = (const int*)d_in[2];
  const float* conv_w = (const float*)d_in[3];
  const float* conv_b = (const float*)d_in[4];
  const float* lin_w  = (const float*)d_in[5];
  const float* lin_b  = (const float*)d_in[6];
  float* out = (float*)d_out;
  int umax = (out_size - Bb) / (Bb * Dd);

  char* ws = (char*)d_ws;
  char*  Bpack    = ws;                                      // 48*73728 = 3,538,944
  float* partial  = (float*)(ws + 48 * (size_t)STEP_BYTES);  // 4*BU*4 = 512KB
  float* wAv      = partial + 4 * BU;
  float* wBv      = wAv + BU;
  int*   fire_pos = (int*)(wBv + BU);
  int*   nf       = (int*)(fire_pos + BU);

  pack_b_kernel<<<(512 * 64) / 256, 256, 0, stream>>>(conv_w, Bpack);
  conv_mfma_full_kernel<<<1024, 512, 0, stream>>>(xs, Bpack, conv_b, lin_w, partial);
  scan_kernel<<<Bb, 64, 0, stream>>>(partial, lin_b, xlens, ylens, wAv, wBv, fire_pos, nf,
                                     out + (size_t)Bb * umax * Dd);
  if (umax > 0)
    gather_kernel<<<dim3(umax, Bb), 512, 0, stream>>>(xs, wAv, wBv, fire_pos, nf, out, umax);
}

// Round 7
// 271.298 us; speedup vs baseline: 1.3988x; 1.0039x over previous
//
#include <hip/hip_runtime.h>
#include <cstddef>
#include <cstdint>

#define Bb 16
#define Uu 2048
#define Dd 512
#define BU (Bb*Uu)

typedef short bf16x8 __attribute__((ext_vector_type(8)));
typedef float f32x4 __attribute__((ext_vector_type(4)));

#define ROW_BYTES 144                 // 64B h + 64B m + 16B pad
#define A_BYTES 18720                 // 130 rows * 144
#define B_SLICE 18432                 // 128 rows * 144
#define B_BASE (2*A_BYTES)            // 37440
#define STEP_BYTES (512*ROW_BYTES)    // 73728 per (chunk,tap) full-N B block
#define SMEM_BYTES (B_BASE + 2*B_SLICE) // 74304 -> 2 blocks/CU

#define WAITVM(N) asm volatile("s_waitcnt vmcnt(" #N ")" ::: "memory")
#define WAITLGKM0 asm volatile("s_waitcnt lgkmcnt(0)" ::: "memory")

__device__ __forceinline__ unsigned short f2bf(float x){
  unsigned int u = __float_as_uint(x);
  u += 0x7fff + ((u >> 16) & 1);          // RNE
  return (unsigned short)(u >> 16);
}
__device__ __forceinline__ float bf2f(unsigned short b){
  return __uint_as_float(((unsigned int)b) << 16);
}

union U16x8 { unsigned short s[8]; uint4 v; };

__device__ __forceinline__ void split2(float x, unsigned short& h, unsigned short& m){
  h = f2bf(x);
  float r1 = x - bf2f(h);
  m = f2bf(r1);
}

// ---------------- pack conv_w -> Bpack[step=(chunk*3+tap)][n(512)][144B: bh32|bm32|pad]
__global__ __launch_bounds__(256) void pack_b_kernel(const float* __restrict__ conv_w,
                                                     char* __restrict__ Bpack){
  int idx = blockIdx.x * 256 + threadIdx.x;    // < 512*64
  int n = idx >> 6, cg = idx & 63;
  int chunk = cg >> 2, sub = cg & 3, c0 = cg << 3;
  const float* src = conv_w + (size_t)n * (Dd * 3) + (size_t)c0 * 3;
  float w[24];
  #pragma unroll
  for (int j = 0; j < 24; ++j) w[j] = src[j];
  #pragma unroll
  for (int tap = 0; tap < 3; ++tap){
    U16x8 H, M;
    #pragma unroll
    for (int j = 0; j < 8; ++j) split2(w[j * 3 + tap], H.s[j], M.s[j]);
    char* dst = Bpack + (size_t)(chunk * 3 + tap) * STEP_BYTES + n * ROW_BYTES + sub * 16;
    *(uint4*)dst = H.v;
    *(uint4*)(dst + 64) = M.v;
  }
}

// ---------------- helpers (256-thread block versions)
__device__ __forceinline__ void stage_A_direct(char* abuf, const float* __restrict__ xsb,
                                               int u0, int c0, int tid){
  #pragma unroll
  for (int it = 0; it < 3; ++it){
    if (it < 2 || tid < 8){
      int t = (it < 2) ? (tid + it * 256) : (512 + tid);
      int r = t >> 2, cg = t & 3;
      int uu = u0 - 1 + r;
      float x[8];
      if (uu >= 0 && uu < Uu){
        const float* p = xsb + (size_t)uu * Dd + c0 + cg * 8;
        float4 a = *(const float4*)p;
        float4 b = *(const float4*)(p + 4);
        x[0]=a.x; x[1]=a.y; x[2]=a.z; x[3]=a.w; x[4]=b.x; x[5]=b.y; x[6]=b.z; x[7]=b.w;
      } else {
        #pragma unroll
        for (int j = 0; j < 8; ++j) x[j] = 0.f;
      }
      U16x8 H, M;
      #pragma unroll
      for (int j = 0; j < 8; ++j) split2(x[j], H.s[j], M.s[j]);
      char* dst = abuf + r * ROW_BYTES + cg * 16;
      *(uint4*)(dst)      = H.v;
      *(uint4*)(dst + 64) = M.v;
    }
  }
}

__device__ __forceinline__ void gll16(const char* g, char* l){
  __builtin_amdgcn_global_load_lds(
      (const __attribute__((address_space(1))) unsigned int*)g,
      (__attribute__((address_space(3))) unsigned int*)l, 16, 0, 0);
}

// 18432B slice = 18 groups of 1024B; 4 waves: wave wv -> groups wv,wv+4,wv+8,wv+12 (+16+wv if wv<2)
// vm issues per wave: wv<2 -> 5, else 4 (uniform; counted waits rely on this)
__device__ __forceinline__ void stage_slice(char* ldsB, const char* __restrict__ src,
                                            int lane, int wv){
  const char* g = src + wv * 1024 + lane * 16;
  char* l = ldsB + wv * 1024;
  gll16(g, l);
  gll16(g + 4096,  l + 4096);
  gll16(g + 8192,  l + 8192);
  gll16(g + 12288, l + 12288);
  if (wv < 2) gll16(g + 16384, l + 16384);
}

__device__ __forceinline__ bf16x8 ldfrag(const char* p){
  return __builtin_bit_cast(bf16x8, *(const uint4*)p);
}

// ---------------- conv GEMM: 128x128 tile, 4 waves x (64x64), 2 blocks/CU,
// A+B double-buffered, 4-pass bf16x2 split, counted-vmcnt pipeline
__global__ __launch_bounds__(256, 2) void conv_mfma_full_kernel(
    const float* __restrict__ xs, const char* __restrict__ Bpack,
    const float* __restrict__ conv_b, const float* __restrict__ lin_w,
    float* __restrict__ partial)
{
  __shared__ __align__(16) char smem[SMEM_BYTES];
  const int tid = threadIdx.x;
  const int lane = tid & 63, wv = tid >> 6;
  const int wm = wv >> 1;                     // 2 M-groups of 64 rows
  const int wn = wv & 1;                      // 2 N-groups of 64 cols
  const int cs = blockIdx.x >> 8;             // col slice 0..3
  const int bt = blockIdx.x & 255;
  const int b = bt >> 4, ut = bt & 15;
  const int u0 = ut * 128;
  const float* xsb = xs + (size_t)b * Uu * Dd;
  const int li = lane & 15, lg = lane >> 4;

  f32x4 acc[4][4];
  #pragma unroll
  for (int m = 0; m < 4; ++m)
    #pragma unroll
    for (int n = 0; n < 4; ++n){
      f32x4 z = {0.f, 0.f, 0.f, 0.f};
      acc[m][n] = z;
    }

  // prologue: A chunk0 -> Abuf0 (plain stores), B step0 -> Bbuf0; full drain once
  stage_A_direct(smem, xsb, u0, 0, tid);
  stage_slice(smem + B_BASE, Bpack + cs * B_SLICE, lane, wv);
  __syncthreads();

  for (int chunk = 0; chunk < 16; ++chunk){
    const bool more = (chunk < 15);
    const char* aC = smem + (chunk & 1) * A_BYTES;
    char* aN = smem + ((chunk & 1) ^ 1) * A_BYTES;
    #pragma unroll
    for (int tap = 0; tap < 3; ++tap){
      const int p = chunk * 3 + tap;
      const int bbuf = p & 1;
      const bool apf_now = (tap == 2) && more;

      // 1. A-prefetch for next chunk (issued before stage; uniform per-wave vm counts)
      float4 pa0, pa1, pb0, pb1, pe0, pe1;
      int rA = 0, cgA = 0;
      if (apf_now){
        const float4 z4 = make_float4(0.f,0.f,0.f,0.f);
        pa0 = z4; pa1 = z4; pe0 = z4; pe1 = z4;
        int c0n = (chunk + 1) * 32;
        rA = tid >> 2; cgA = tid & 3;
        int uuA = u0 - 1 + rA;                 // rows 0..63 (task A)
        if (uuA >= 0){
          const float* pp = xsb + (size_t)uuA * Dd + c0n + cgA * 8;
          pa0 = *(const float4*)pp;
          pa1 = *(const float4*)(pp + 4);
        }
        {                                      // rows 64..127 (task B, always valid)
          const float* pp = xsb + (size_t)(u0 + 63 + rA) * Dd + c0n + cgA * 8;
          pb0 = *(const float4*)pp;
          pb1 = *(const float4*)(pp + 4);
        }
        if (wv == 0){                          // rows 128,129 (extra, wave0 lanes 0-7)
          int rE = 128 + (lane >> 2);
          int uuE = u0 - 1 + rE;
          if (lane < 8 && uuE < Uu){
            const float* pp = xsb + (size_t)uuE * Dd + c0n + (lane & 3) * 8;
            pe0 = *(const float4*)pp;
            pe1 = *(const float4*)(pp + 4);
          }
        }
        __builtin_amdgcn_sched_barrier(0);
      }

      // 2. stage next step's B slice into the other buffer (5/5/4/4 loads per wave)
      if (p < 47)
        stage_slice(smem + B_BASE + (bbuf ^ 1) * B_SLICE,
                    Bpack + (size_t)(p + 1) * STEP_BYTES + cs * B_SLICE, lane, wv);

      // 3. counted wait: retire stage(p); leave stage(p+1) [+apf until after MFMA]
      if (p == 47)            { WAITVM(0); }
      else if (apf_now)       { if (wv == 0) WAITVM(11); else if (wv == 1) WAITVM(9); else WAITVM(8); }
      else                    { if (wv < 2) WAITVM(5); else WAITVM(4); }
      __builtin_amdgcn_sched_barrier(0);

      // 4. A fragments (tap-shifted rows), 2 splits, 4 m-groups
      bf16x8 a[4][2];
      #pragma unroll
      for (int m = 0; m < 4; ++m){
        const char* ar = aC + (size_t)(wm * 64 + m * 16 + li + tap) * ROW_BYTES + lg * 16;
        a[m][0] = ldfrag(ar);
        a[m][1] = ldfrag(ar + 64);
      }

      // 5. B fragments + MFMA (4-pass split, m-innermost so same-acc deps are 4 apart)
      __builtin_amdgcn_s_setprio(1);
      const char* bbase = smem + B_BASE + bbuf * B_SLICE;
      #pragma unroll
      for (int n = 0; n < 4; ++n){
        const char* br = bbase + (size_t)(wn * 64 + n * 16 + li) * ROW_BYTES + lg * 16;
        bf16x8 bh = ldfrag(br);
        bf16x8 bm = ldfrag(br + 64);
        #pragma unroll
        for (int m = 0; m < 4; ++m) acc[m][n] = __builtin_amdgcn_mfma_f32_16x16x32_bf16(a[m][0], bh, acc[m][n], 0, 0, 0); // hh
        #pragma unroll
        for (int m = 0; m < 4; ++m) acc[m][n] = __builtin_amdgcn_mfma_f32_16x16x32_bf16(a[m][1], bh, acc[m][n], 0, 0, 0); // mh
        #pragma unroll
        for (int m = 0; m < 4; ++m) acc[m][n] = __builtin_amdgcn_mfma_f32_16x16x32_bf16(a[m][0], bm, acc[m][n], 0, 0, 0); // hm
        #pragma unroll
        for (int m = 0; m < 4; ++m) acc[m][n] = __builtin_amdgcn_mfma_f32_16x16x32_bf16(a[m][1], bm, acc[m][n], 0, 0, 0); // mm
      }
      __builtin_amdgcn_s_setprio(0);

      // 6. tap2: retire apf (keep stage(p+1)), convert+write next chunk's A to other buffer
      if (apf_now){
        if (wv < 2) { WAITVM(5); } else { WAITVM(4); }
        __builtin_amdgcn_sched_barrier(0);
        U16x8 H, M;
        float x[8];
        x[0]=pa0.x; x[1]=pa0.y; x[2]=pa0.z; x[3]=pa0.w;
        x[4]=pa1.x; x[5]=pa1.y; x[6]=pa1.z; x[7]=pa1.w;
        #pragma unroll
        for (int jj = 0; jj < 8; ++jj) split2(x[jj], H.s[jj], M.s[jj]);
        char* dst = aN + rA * ROW_BYTES + cgA * 16;
        *(uint4*)(dst)      = H.v;
        *(uint4*)(dst + 64) = M.v;
        x[0]=pb0.x; x[1]=pb0.y; x[2]=pb0.z; x[3]=pb0.w;
        x[4]=pb1.x; x[5]=pb1.y; x[6]=pb1.z; x[7]=pb1.w;
        #pragma unroll
        for (int jj = 0; jj < 8; ++jj) split2(x[jj], H.s[jj], M.s[jj]);
        char* dst2 = aN + (64 + rA) * ROW_BYTES + cgA * 16;
        *(uint4*)(dst2)      = H.v;
        *(uint4*)(dst2 + 64) = M.v;
        if (wv == 0){
          if (lane < 8){
            float y[8];
            y[0]=pe0.x; y[1]=pe0.y; y[2]=pe0.z; y[3]=pe0.w;
            y[4]=pe1.x; y[5]=pe1.y; y[6]=pe1.z; y[7]=pe1.w;
            #pragma unroll
            for (int jj = 0; jj < 8; ++jj) split2(y[jj], H.s[jj], M.s[jj]);
            char* dst3 = aN + (128 + (lane >> 2)) * ROW_BYTES + (lane & 3) * 16;
            *(uint4*)(dst3)      = H.v;
            *(uint4*)(dst3 + 64) = M.v;
          }
        }
        WAITLGKM0;                            // A-writes visible before phase-end barrier
        __builtin_amdgcn_sched_barrier(0);
      }
      __builtin_amdgcn_s_barrier();           // phase end (stage(p+1) stays in flight)
    }
  }

  // ---- epilogue: relu(h+conv_b)*lin_w partial dot over this block's 128 cols
  __syncthreads();
  float* pbuf = (float*)smem;                 // [128 frames][2]
  #pragma unroll
  for (int m = 0; m < 4; ++m){
    float s0 = 0.f, s1 = 0.f, s2 = 0.f, s3 = 0.f;
    #pragma unroll
    for (int n = 0; n < 4; ++n){
      int col = cs * 128 + wn * 64 + n * 16 + li;
      float cb = conv_b[col], lw = lin_w[col];
      f32x4 v = acc[m][n];
      float h;
      h = v[0] + cb; h = h > 0.f ? h : 0.f; s0 += h * lw;
      h = v[1] + cb; h = h > 0.f ? h : 0.f; s1 += h * lw;
      h = v[2] + cb; h = h > 0.f ? h : 0.f; s2 += h * lw;
      h = v[3] + cb; h = h > 0.f ? h : 0.f; s3 += h * lw;
    }
    #pragma unroll
    for (int msk = 1; msk < 16; msk <<= 1){
      s0 += __shfl_xor(s0, msk); s1 += __shfl_xor(s1, msk);
      s2 += __shfl_xor(s2, msk); s3 += __shfl_xor(s3, msk);
    }
    if (li == 0){
      int fr = wm * 64 + m * 16 + lg * 4;
      pbuf[(fr + 0) * 2 + wn] = s0;
      pbuf[(fr + 1) * 2 + wn] = s1;
      pbuf[(fr + 2) * 2 + wn] = s2;
      pbuf[(fr + 3) * 2 + wn] = s3;
    }
  }
  __syncthreads();
  if (tid < 128){
    float pv = pbuf[tid * 2] + pbuf[tid * 2 + 1];
    partial[(size_t)cs * BU + (size_t)b * Uu + u0 + tid] = pv;
  }
}

// ---------------- fused alpha + scalar-chain scan (one wave per batch) — unchanged (passed R6)
__global__ __launch_bounds__(64) void scan_kernel(
    const float* __restrict__ partial, const float* __restrict__ lin_b,
    const int* __restrict__ xlens, const int* __restrict__ ylens,
    float* __restrict__ wA, float* __restrict__ wB,
    int* __restrict__ fire_pos, int* __restrict__ nf,
    float* __restrict__ out_sum)
{
  __shared__ float salpha[Uu];
  int b = blockIdx.x;
  int lane = threadIdx.x;
  int xl = xlens[b];
  float lb = lin_b[0];

  float sum = 0.f;
  for (int u0 = 0; u0 < Uu; u0 += 64){
    int u = u0 + lane;
    size_t ix = (size_t)b * Uu + u;
    float v = lb + partial[ix] + partial[BU + ix] + partial[2 * BU + ix] + partial[3 * BU + ix];
    float a = 1.f / (1.f + expf(-v));
    if (u >= xl) a = 0.f;
    salpha[u] = a;
    sum += a;
  }
  #pragma unroll
  for (int m = 1; m < 64; m <<= 1) sum += __shfl_xor(sum, m);
  float sa = sum;
  float beta = sa / (float)ylens[b] - 1e-4f;
  if (lane == 0) out_sum[b] = sa;

  float prev = 0.f;
  int cnt = 0;
  for (int u0 = 0; u0 < Uu; u0 += 64) {
    if (u0 >= xl) break;
    float val = salpha[u0 + lane];
    float mywa = 0.f, mywb = 0.f;
    #pragma unroll
    for (int i = 0; i < 64; ++i) {
      float a_cur = __builtin_bit_cast(float,
          __builtin_amdgcn_readlane(__builtin_bit_cast(int, val), i));
      float nw = prev + a_cur;
      float left = beta - prev;
      float right = nw - beta;
      bool fired = nw >= beta;
      if (lane == i) { mywa = left; mywb = right; }
      if (fired) {
        if (lane == 0) fire_pos[(b << 11) + cnt] = u0 + i;
        ++cnt;
      }
      prev = fired ? right : nw;
    }
    wA[(size_t)b * Uu + u0 + lane] = mywa;
    wB[(size_t)b * Uu + u0 + lane] = mywb;
  }
  if (lane == 0) nf[b] = cnt;
}

// ---------------- segmented gather -> h_cif — unchanged (passed)
__global__ __launch_bounds__(512) void gather_kernel(
    const float* __restrict__ xs, const float* __restrict__ wA, const float* __restrict__ wB,
    const int* __restrict__ fire_pos, const int* __restrict__ nf,
    float* __restrict__ out, int umax)
{
  int t = blockIdx.x, b = blockIdx.y;
  int tid = threadIdx.x;
  float* o = out + ((size_t)b * umax + t) * Dd;
  int n = nf[b];
  if (t >= n) { o[tid] = 0.f; return; }
  int start = (t == 0) ? 0 : fire_pos[(b << 11) + t - 1];
  int end = fire_pos[(b << 11) + t];
  const float* xb = xs + (size_t)b * Uu * Dd;
  float acc = 0.f;
  for (int u = start; u <= end; ++u) {
    float w = (t > 0 && u == start) ? wB[(size_t)b * Uu + u] : wA[(size_t)b * Uu + u];
    acc += w * xb[(size_t)u * Dd + tid];
  }
  o[tid] = acc;
}

extern "C" void kernel_launch(void* const* d_in, const int* in_sizes, int n_in,
                              void* d_out, int out_size, void* d_ws, size_t ws_size,
                              hipStream_t stream) {
  const float* xs     = (const float*)d_in[0];
  const int*   xlens  = (const int*)d_in[1];
  const int*   ylens  = (const int*)d_in[2];
  const float* conv_w = (const float*)d_in[3];
  const float* conv_b = (const float*)d_in[4];
  const float* lin_w  = (const float*)d_in[5];
  const float* lin_b  = (const float*)d_in[6];
  float* out = (float*)d_out;
  int umax = (out_size - Bb) / (Bb * Dd);

  char* ws = (char*)d_ws;
  char*  Bpack    = ws;                                      // 48*73728 = 3,538,944
  float* partial  = (float*)(ws + 48 * (size_t)STEP_BYTES);  // 4*BU*4 = 512KB
  float* wAv      = partial + 4 * BU;
  float* wBv      = wAv + BU;
  int*   fire_pos = (int*)(wBv + BU);
  int*   nf       = (int*)(fire_pos + BU);

  pack_b_kernel<<<(512 * 64) / 256, 256, 0, stream>>>(conv_w, Bpack);
  conv_mfma_full_kernel<<<1024, 256, 0, stream>>>(xs, Bpack, conv_b, lin_w, partial);
  scan_kernel<<<Bb, 64, 0, stream>>>(partial, lin_b, xlens, ylens, wAv, wBv, fire_pos, nf,
                                     out + (size_t)Bb * umax * Dd);
  if (umax > 0)
    gather_kernel<<<dim3(umax, Bb), 512, 0, stream>>>(xs, wAv, wBv, fire_pos, nf, out, umax);
}